// Round 9
// baseline (643.263 us; speedup 1.0000x reference)
//
#include <hip/hip_runtime.h>
#include <stdint.h>

#define NNODES 50000
#define NEDGES 1600000
#define HD 256
#define EPSV 1e-5f
#define CAP 80    // u16 bucket CSR stride; deg ~ Poisson(32), P(deg>=79) ~ 1e-11
#define FILLB 1563  // ceil(NEDGES/4/256) fill blocks (4 edges/thread)

typedef unsigned short u16;
typedef __attribute__((ext_vector_type(8))) short short8;
typedef __attribute__((ext_vector_type(4))) float f32x4;

__device__ __forceinline__ u16 f2b(float f) {
  union { float f; uint32_t u; } c; c.f = f;
  uint32_t u = c.u;
  u += 0x7fffu + ((u >> 16) & 1u);   // round-to-nearest-even
  return (u16)(u >> 16);
}
__device__ __forceinline__ float b2f(u16 s) {
  union { uint32_t u; float f; } c; c.u = ((uint32_t)s) << 16;
  return c.f;
}

// async 16B global -> LDS (direct-to-shared DMA). LDS dst must be
// wave-uniform base + lane*16 — our tid*16 flat mappings satisfy this.
__device__ __forceinline__ void gl2lds16(const u16* g, u16* l) {
  __builtin_amdgcn_global_load_lds(
      (__attribute__((address_space(1))) void*)(void*)g,
      (__attribute__((address_space(3))) void*)(void*)l, 16, 0, 0);
}

// ---------------- small setup kernels ----------------

// st layout: 4 stat-sets x 8 slices x 512 floats (sum | sumsq per col)
// cur[i]=1 and csr[i*CAP]=i: self-loop pre-seeded, cur is both the fill
// cursor and (after fill) the node degree.
__global__ void init_k(int* __restrict__ cur, u16* __restrict__ csr, float* __restrict__ st) {
  int i = blockIdx.x * 256 + threadIdx.x;
  if (i < NNODES) { cur[i] = 1; csr[(size_t)i * CAP] = (u16)i; }
  if (i < 4 * 8 * 512) st[i] = 0.f;
}

// w1 [168,256] fp32 -> W1T [256][192] bf16 (k-contiguous, zero-padded K)
__global__ void cw1_k(const float* __restrict__ w1, u16* __restrict__ W1T) {
  int n = blockIdx.x, k = threadIdx.x;  // block 192 threads
  W1T[n * 192 + k] = (k < 168) ? f2b(w1[k * HD + n]) : (u16)0;
}

// Mc [256][192] = [tbW@basis_b || tfW@basis_f]
__global__ void mc_k(const float* __restrict__ tbW, const float* __restrict__ tfW,
                     const float* __restrict__ bb, const float* __restrict__ bf,
                     float* __restrict__ Mc) {
  int k = blockIdx.x, n = threadIdx.x;  // block 192 threads
  float s = 0.f;
  if (n < 168) {
    for (int i = 0; i < 167; ++i) s += tbW[k * 167 + i] * bb[i * 168 + n];
  } else {
    int n2 = n - 168;
    for (int i = 0; i < 23; ++i) s += tfW[k * 23 + i] * bf[i * 24 + n2];
  }
  Mc[k * 192 + n] = s;
}

__global__ void dinv_k(const int* __restrict__ cur, float* __restrict__ dinv) {
  int i = blockIdx.x * 256 + threadIdx.x;
  if (i < NNODES) dinv[i] = rsqrtf((float)cur[i]);
}

// ---------------- MFMA GEMM: [M x K] @ WT^T -> [M x NT*16] cols/blk -------
// WT is [256][Kpad] bf16, k-contiguous (pre-transposed, BN-folded).
// NCB col-blocks per 64-row tile: block covers cols [col0, col0+NT*16).
// A (bf16 path) and B staged via async global_load_lds width=16.
// Epilogue: + extra[col]; optional ReLU; optional *dinv[row]; store bf16,
// or (SPLIT) fp32 split to backcast/forecast. STATS: fused BN sum/sumsq.
// FILL: first FILLB blocks run the bucket-CSR fill concurrently, 4 edges
// per thread (int4 load, 4 independent atomic->store latency chains) —
// fill is latency-bound (was ILP=1, 4 VGPRs) and co-schedules with the
// compute-bound gemm. Fill blocks lead the grid so their chains overlap
// gemm compute from dispatch round 0.
template <int NT, int NCB, bool AF32, bool RELU, bool SPLIT, bool DSCALE, bool STATS, bool FILL>
__global__ __launch_bounds__(256) void gemm_k(const void* __restrict__ Ap, int M, int Kpad,
                                              int lda, int Klim,
                                              const u16* __restrict__ WT,
                                              const float* __restrict__ extra,
                                              const float* __restrict__ dinv,
                                              void* __restrict__ outp, float* __restrict__ out2,
                                              float* __restrict__ stout,
                                              const int* __restrict__ esrc,
                                              const int* __restrict__ edst,
                                              int* __restrict__ fcur, u16* __restrict__ fcsr) {
  constexpr int BROWS = NT * 16;
  int bid = (int)blockIdx.x;
  if constexpr (FILL) {
    if (bid < FILLB) {   // block-uniform branch; returns before any __syncthreads
      int e0 = (bid * 256 + (int)threadIdx.x) * 4;
      if (e0 < NEDGES) {
        int4 dv = *(const int4*)&edst[e0];
        int4 sv = *(const int4*)&esrc[e0];
        int p0 = atomicAdd(&fcur[dv.x], 1);
        int p1 = atomicAdd(&fcur[dv.y], 1);
        int p2 = atomicAdd(&fcur[dv.z], 1);
        int p3 = atomicAdd(&fcur[dv.w], 1);
        if (p0 < CAP) fcsr[(size_t)dv.x * CAP + p0] = (u16)sv.x;
        if (p1 < CAP) fcsr[(size_t)dv.y * CAP + p1] = (u16)sv.y;
        if (p2 < CAP) fcsr[(size_t)dv.z * CAP + p2] = (u16)sv.z;
        if (p3 < CAP) fcsr[(size_t)dv.w * CAP + p3] = (u16)sv.w;
      }
      return;
    }
    bid -= FILLB;
  }
  __shared__ __align__(16) u16 Alds[64][32];
  __shared__ __align__(16) u16 Blds[BROWS][32];
  constexpr int SR = STATS ? 4 : 1;
  constexpr int SC = STATS ? BROWS : 1;
  __shared__ float sred[SR][SC];
  __shared__ float qred[SR][SC];
  const int tid = threadIdx.x;
  const int wave = tid >> 6, lane = tid & 63;
  const int quad = lane >> 4, l16 = lane & 15;
  const int cb = bid % NCB;
  const int row0 = (bid / NCB) * 64;
  const int col0 = cb * BROWS;

  f32x4 acc[NT];
#pragma unroll
  for (int i = 0; i < NT; ++i) acc[i] = (f32x4){0.f, 0.f, 0.f, 0.f};

  const int am = tid >> 2;            // 0..63 tile row
  const int akc = (tid & 3) * 8;      // 0,8,16,24 k-chunk
  const int arow = row0 + am;

  for (int k0 = 0; k0 < Kpad; k0 += 32) {
    // --- stage A tile [64][32]: LDS flat offset = tid*16B (row-major) ---
    if constexpr (AF32) {
      uint4 pack = {0u, 0u, 0u, 0u};
      const float* A = (const float*)Ap;
      if (arow < M && (k0 + akc) < Klim) {
        const float* p = A + (size_t)arow * lda + k0 + akc;
        float4 fa = *(const float4*)p;
        float4 fb = *(const float4*)(p + 4);
        pack.x = (uint32_t)f2b(fa.x) | ((uint32_t)f2b(fa.y) << 16);
        pack.y = (uint32_t)f2b(fa.z) | ((uint32_t)f2b(fa.w) << 16);
        pack.z = (uint32_t)f2b(fb.x) | ((uint32_t)f2b(fb.y) << 16);
        pack.w = (uint32_t)f2b(fb.z) | ((uint32_t)f2b(fb.w) << 16);
      }
      *(uint4*)&Alds[am][akc] = pack;
    } else {
      const u16* A = (const u16*)Ap;
      if (arow < M)
        gl2lds16(A + (size_t)arow * lda + k0 + akc, &Alds[0][0] + (size_t)tid * 8);
      // rows >= M: stale LDS feeds only discarded acc rows
    }
    // --- stage B tile [BROWS][32]: issue i covers rows i*64+(tid>>2) ---
#pragma unroll
    for (int i = 0; i < (BROWS + 63) / 64; ++i) {
      int br = i * 64 + am;
      if (br < BROWS)
        gl2lds16(WT + (size_t)(col0 + br) * Kpad + k0 + akc,
                 &Blds[0][0] + (size_t)i * 2048 + (size_t)tid * 8);
    }
    __syncthreads();   // drains vmcnt -> LDS writes visible
    short8 av = *(const short8*)&Alds[wave * 16 + l16][quad * 8];
#pragma unroll
    for (int nt = 0; nt < NT; ++nt) {
      short8 bv = *(const short8*)&Blds[nt * 16 + l16][quad * 8];
      acc[nt] = __builtin_amdgcn_mfma_f32_16x16x32_bf16(av, bv, acc[nt], 0, 0, 0);
    }
    __syncthreads();
  }

  // --- epilogue: C/D layout col = lane&15, row = quad*4 + reg ---
#pragma unroll
  for (int nt = 0; nt < NT; ++nt) {
    float s = 0.f, q = 0.f;
    int col = col0 + nt * 16 + l16;
#pragma unroll
    for (int r = 0; r < 4; ++r) {
      int row = row0 + wave * 16 + quad * 4 + r;
      if (row >= M) continue;
      float v = acc[nt][r] + extra[col];
      if constexpr (RELU) v = fmaxf(v, 0.f);
      if constexpr (DSCALE) v *= dinv[row];   // GCN: pre-scale row by dinv[src]
      if constexpr (SPLIT) {
        if (col < 168) ((float*)outp)[(size_t)row * 168 + col] = v;
        else ((float*)out2)[(size_t)row * 24 + (col - 168)] = v;
      } else {
        ((u16*)outp)[(size_t)row * HD + col] = f2b(v);
      }
      if constexpr (STATS) { s += v; q += v * v; }
    }
    if constexpr (STATS) {
      // reduce over the wave's 16 rows (quads 0..3 share l16 -> same col)
      s += __shfl_xor(s, 16); s += __shfl_xor(s, 32);
      q += __shfl_xor(q, 16); q += __shfl_xor(q, 32);
      if (quad == 0) { sred[wave][nt * 16 + l16] = s; qred[wave][nt * 16 + l16] = q; }
    }
  }
  if constexpr (STATS) {
    __syncthreads();
    if (tid < BROWS) {
      float s = sred[0][tid] + sred[1][tid] + sred[2][tid] + sred[3][tid];
      float q = qred[0][tid] + qred[1][tid] + qred[2][tid] + qred[3][tid];
      int sl = (bid & 7) * 512;   // 8-way sliced accumulators
      atomicAdd(&stout[sl + col0 + tid], s);
      atomicAdd(&stout[sl + 256 + col0 + tid], q);
    }
  }
}

// ---------------- fold BN(stats,gamma,beta) into next weight ----------------
// stats arrive as 8 slices of [512] (sum | sumsq); sum the slices here.
__global__ __launch_bounds__(256) void fold_k(const float* __restrict__ st, float invM,
                                              const float* __restrict__ gamma,
                                              const float* __restrict__ beta,
                                              const float* __restrict__ W, int ncols,
                                              const float* __restrict__ bias,
                                              u16* __restrict__ WT, float* __restrict__ extra) {
  int n = blockIdx.x, k = threadIdx.x;
  float sm = 0.f, sq = 0.f;
#pragma unroll
  for (int s = 0; s < 8; ++s) { sm += st[s * 512 + k]; sq += st[s * 512 + 256 + k]; }
  float m = sm * invM;
  float v = sq * invM - m * m;
  float sc = gamma[k] * rsqrtf(v + EPSV);
  float sh = beta[k] - m * sc;
  float w = W[(size_t)k * ncols + n];
  WT[(size_t)n * HD + k] = f2b(sc * w);
  __shared__ float red[256];
  red[k] = sh * w;
  __syncthreads();
  for (int d = 128; d > 0; d >>= 1) {
    if (k < d) red[k] += red[k + d];
    __syncthreads();
  }
  if (k == 0) extra[n] = (bias ? bias[n] : 0.f) + red[0];
}

// ---------------- GCN aggregation: one wave per dst node ----------------
// xw rows are PRE-SCALED by dinv[src] in the gemm epilogue, so the inner
// loop is a pure gather-sum. 8-deep software pipeline to hide gather latency.
// BN stats fused into the epilogue. Bucket CSR (u16): node d's list is
// csr[d*CAP .. d*CAP+deg), deg = cur[d]; rows are 160B (16B-aligned).
__global__ __launch_bounds__(256) void agg_k(const u16* __restrict__ csr,
                                             const int* __restrict__ deg,
                                             const float* __restrict__ dinv, const u16* __restrict__ xw,
                                             const float* __restrict__ gb, u16* __restrict__ out,
                                             float* __restrict__ stout) {
  __shared__ float ss[4][256];
  __shared__ float qq[4][256];
  int wave = threadIdx.x >> 6, lane = threadIdx.x & 63;
  int dst = blockIdx.x * 4 + wave;
  bool valid = dst < NNODES;
  const int c = lane * 4;
  float r0 = 0.f, r1 = 0.f, r2 = 0.f, r3 = 0.f;
  if (valid) {
    int p0 = dst * CAP;
    int p1 = p0 + min(deg[dst], CAP);
    float a0 = 0.f, a1 = 0.f, a2 = 0.f, a3 = 0.f;
    int p = p0;
#define ACCUM(vv)                              \
  a0 += b2f((u16)((vv).x & 0xffffu));          \
  a1 += b2f((u16)((vv).x >> 16));              \
  a2 += b2f((u16)((vv).y & 0xffffu));          \
  a3 += b2f((u16)((vv).y >> 16));
    for (; p + 8 <= p1; p += 8) {
      uint4 sw = *(const uint4*)&csr[p];   // 8 u16 indices
      int s0 = sw.x & 0xffff, s1 = sw.x >> 16;
      int s2 = sw.y & 0xffff, s3 = sw.y >> 16;
      int s4 = sw.z & 0xffff, s5 = sw.z >> 16;
      int s6 = sw.w & 0xffff, s7 = sw.w >> 16;
      uint2 v0 = *(const uint2*)&xw[(size_t)s0 * HD + c];
      uint2 v1 = *(const uint2*)&xw[(size_t)s1 * HD + c];
      uint2 v2 = *(const uint2*)&xw[(size_t)s2 * HD + c];
      uint2 v3 = *(const uint2*)&xw[(size_t)s3 * HD + c];
      uint2 v4 = *(const uint2*)&xw[(size_t)s4 * HD + c];
      uint2 v5 = *(const uint2*)&xw[(size_t)s5 * HD + c];
      uint2 v6 = *(const uint2*)&xw[(size_t)s6 * HD + c];
      uint2 v7 = *(const uint2*)&xw[(size_t)s7 * HD + c];
      ACCUM(v0); ACCUM(v1); ACCUM(v2); ACCUM(v3);
      ACCUM(v4); ACCUM(v5); ACCUM(v6); ACCUM(v7);
    }
    for (; p < p1; ++p) {
      int s = csr[p];
      uint2 v = *(const uint2*)&xw[(size_t)s * HD + c];
      ACCUM(v);
    }
#undef ACCUM
    float dd = dinv[dst];
    float4 gv = *(const float4*)&gb[c];
    r0 = fmaxf(dd * a0 + gv.x, 0.f);
    r1 = fmaxf(dd * a1 + gv.y, 0.f);
    r2 = fmaxf(dd * a2 + gv.z, 0.f);
    r3 = fmaxf(dd * a3 + gv.w, 0.f);
    uint2 o;
    o.x = (uint32_t)f2b(r0) | ((uint32_t)f2b(r1) << 16);
    o.y = (uint32_t)f2b(r2) | ((uint32_t)f2b(r3) << 16);
    *(uint2*)&out[(size_t)dst * HD + c] = o;
  }
  // fused BN stats: reduce 4 waves' rows in LDS, one sliced atomic per col
  ss[wave][c + 0] = r0; ss[wave][c + 1] = r1; ss[wave][c + 2] = r2; ss[wave][c + 3] = r3;
  qq[wave][c + 0] = r0 * r0; qq[wave][c + 1] = r1 * r1;
  qq[wave][c + 2] = r2 * r2; qq[wave][c + 3] = r3 * r3;
  __syncthreads();
  int t = threadIdx.x;
  float s = ss[0][t] + ss[1][t] + ss[2][t] + ss[3][t];
  float q = qq[0][t] + qq[1][t] + qq[2][t] + qq[3][t];
  int sl = (blockIdx.x & 7) * 512;
  atomicAdd(&stout[sl + t], s);
  atomicAdd(&stout[sl + 256 + t], q);
}

// ---------------- launch ----------------

extern "C" void kernel_launch(void* const* d_in, const int* in_sizes, int n_in,
                              void* d_out, int out_size, void* d_ws, size_t ws_size,
                              hipStream_t stream) {
  const float* x = (const float*)d_in[0];
  const int* ei = (const int*)d_in[1];
  const float* w1 = (const float*)d_in[2];
  const float* b1 = (const float*)d_in[3];
  const float* g1 = (const float*)d_in[4];
  const float* bt1 = (const float*)d_in[5];
  const float* w2 = (const float*)d_in[6];
  const float* b2 = (const float*)d_in[7];
  const float* g2 = (const float*)d_in[8];
  const float* bt2 = (const float*)d_in[9];
  const float* gw1 = (const float*)d_in[10];
  const float* gb1 = (const float*)d_in[11];
  const float* gg1 = (const float*)d_in[12];
  const float* gbt1 = (const float*)d_in[13];
  const float* gw2 = (const float*)d_in[14];
  const float* gb2 = (const float*)d_in[15];
  const float* gg2 = (const float*)d_in[16];
  const float* gbt2 = (const float*)d_in[17];
  const float* tbW = (const float*)d_in[18];
  const float* tfW = (const float*)d_in[19];
  const float* bb = (const float*)d_in[20];
  const float* bfb = (const float*)d_in[21];
  const int* esrc = ei;
  const int* edst = ei + NEDGES;

  char* wsp = (char*)d_ws;
  size_t off = 0;
  auto alloc = [&](size_t b) {
    void* p = wsp + off;
    off += (b + 511) & ~(size_t)511;
    return p;
  };
  u16* buf1 = (u16*)alloc((size_t)NNODES * HD * 2);
  u16* buf2 = (u16*)alloc((size_t)NNODES * HD * 2);
  u16* csr = (u16*)alloc((size_t)NNODES * CAP * 2);
  int* cur = (int*)alloc((size_t)NNODES * 4);
  float* dinv = (float*)alloc((size_t)NNODES * 4);
  float* st = (float*)alloc((size_t)4 * 8 * 512 * 4);   // 4 sets x 8 slices x 512
  u16* W1T = (u16*)alloc(256 * 192 * 2);
  u16* WT = (u16*)alloc(256 * 256 * 2);
  float* Mc = (float*)alloc(256 * 192 * 4);
  float* extra = (float*)alloc(256 * 4);

  float* backc = (float*)d_out;
  float* forec = backc + (size_t)NNODES * 168;
  const float invM = 1.0f / (float)NNODES;

  const int GB = (NNODES + 63) / 64;  // 782

  init_k<<<196, 256, 0, stream>>>(cur, csr, st);
  cw1_k<<<256, 192, 0, stream>>>(w1, W1T);
  mc_k<<<256, 192, 0, stream>>>(tbW, tfW, bb, bfb, Mc);

  // MLP layer 1 (stats fused) + co-launched CSR fill (4 edges/thread,
  // fill blocks lead the grid and overlap the compute-bound gemm)
  gemm_k<8, 2, true, true, false, false, true, true><<<FILLB + GB * 2, 256, 0, stream>>>(
      x, NNODES, 192, 168, 168, W1T, b1, nullptr, buf1, nullptr, st, esrc, edst, cur, csr);
  dinv_k<<<196, 256, 0, stream>>>(cur, dinv);
  // fold BN1 into w2 (+b2)
  fold_k<<<256, 256, 0, stream>>>(st, invM, g1, bt1, w2, 256, b2, WT, extra);
  // MLP layer 2: a2 = ReLU(BN1(a1)@w2 + b2), stats fused
  gemm_k<8, 2, false, true, false, false, true, false><<<GB * 2, 256, 0, stream>>>(
      buf1, NNODES, 256, 256, 256, WT, extra, nullptr, buf2, nullptr, st + 4096, nullptr, nullptr, nullptr, nullptr);
  // fold BN2 into gw1 (no bias: gb1 added after aggregation)
  fold_k<<<256, 256, 0, stream>>>(st + 4096, invM, g2, bt2, gw1, 256, nullptr, WT, extra);
  // xw1 = (BN2(a2)@gw1) * dinv[row]  (pre-scaled for aggregation)
  gemm_k<8, 2, false, false, false, true, false, false><<<GB * 2, 256, 0, stream>>>(
      buf2, NNODES, 256, 256, 256, WT, extra, dinv, buf1, nullptr, nullptr, nullptr, nullptr, nullptr, nullptr);
  // g1a = ReLU(dinv[dst] * sum(xw1[src]) + gb1), stats fused
  agg_k<<<12500, 256, 0, stream>>>(csr, cur, dinv, buf1, gb1, buf2, st + 8192);
  // fold BN3 into gw2
  fold_k<<<256, 256, 0, stream>>>(st + 8192, invM, gg1, gbt1, gw2, 256, nullptr, WT, extra);
  // xw2 = (BN3(g1a)@gw2) * dinv[row]
  gemm_k<8, 2, false, false, false, true, false, false><<<GB * 2, 256, 0, stream>>>(
      buf2, NNODES, 256, 256, 256, WT, extra, dinv, buf1, nullptr, nullptr, nullptr, nullptr, nullptr, nullptr);
  // g2a = ReLU(dinv[dst] * sum(xw2[src]) + gb2), stats fused
  agg_k<<<12500, 256, 0, stream>>>(csr, cur, dinv, buf1, gb2, buf2, st + 12288);
  // fold BN4 into Mc [256][192]
  fold_k<<<192, 256, 0, stream>>>(st + 12288, invM, gg2, gbt2, Mc, 192, nullptr, WT, extra);
  // final: [backcast || forecast] = BN4(g2a) @ Mc (2 col-blocks of 96)
  gemm_k<6, 2, false, false, true, false, false, false><<<GB * 2, 256, 0, stream>>>(
      buf2, NNODES, 256, 256, 256, WT, extra, nullptr, backc, forec, nullptr, nullptr, nullptr, nullptr, nullptr);
}

// Round 10
// 609.600 us; speedup vs baseline: 1.0552x; 1.0552x over previous
//
#include <hip/hip_runtime.h>
#include <stdint.h>

#define NNODES 50000
#define NEDGES 1600000
#define HD 256
#define EPSV 1e-5f
#define CAP 80    // u16 bucket CSR stride; deg ~ Poisson(32), P(deg>=79) ~ 1e-11

typedef unsigned short u16;
typedef __attribute__((ext_vector_type(8))) short short8;
typedef __attribute__((ext_vector_type(4))) float f32x4;

__device__ __forceinline__ u16 f2b(float f) {
  union { float f; uint32_t u; } c; c.f = f;
  uint32_t u = c.u;
  u += 0x7fffu + ((u >> 16) & 1u);   // round-to-nearest-even
  return (u16)(u >> 16);
}
__device__ __forceinline__ float b2f(u16 s) {
  union { uint32_t u; float f; } c; c.u = ((uint32_t)s) << 16;
  return c.f;
}

// async 16B global -> LDS (direct-to-shared DMA). LDS dst must be
// wave-uniform base + lane*16 — our tid*16 flat mappings satisfy this.
__device__ __forceinline__ void gl2lds16(const u16* g, u16* l) {
  __builtin_amdgcn_global_load_lds(
      (__attribute__((address_space(1))) void*)(void*)g,
      (__attribute__((address_space(3))) void*)(void*)l, 16, 0, 0);
}

// ---------------- small setup kernels ----------------

// st layout: 4 stat-sets x 8 slices x 512 floats (sum | sumsq per col)
// cur[i]=1 and csr[i*CAP]=i: self-loop pre-seeded, cur is both the fill
// cursor and (after fill) the node degree.
__global__ void init_k(int* __restrict__ cur, u16* __restrict__ csr, float* __restrict__ st) {
  int i = blockIdx.x * 256 + threadIdx.x;
  if (i < NNODES) { cur[i] = 1; csr[(size_t)i * CAP] = (u16)i; }
  if (i < 4 * 8 * 512) st[i] = 0.f;
}

// w1 [168,256] fp32 -> W1T [256][192] bf16 (k-contiguous, zero-padded K)
__global__ void cw1_k(const float* __restrict__ w1, u16* __restrict__ W1T) {
  int n = blockIdx.x, k = threadIdx.x;  // block 192 threads
  W1T[n * 192 + k] = (k < 168) ? f2b(w1[k * HD + n]) : (u16)0;
}

// Mc [256][192] = [tbW@basis_b || tfW@basis_f]
__global__ void mc_k(const float* __restrict__ tbW, const float* __restrict__ tfW,
                     const float* __restrict__ bb, const float* __restrict__ bf,
                     float* __restrict__ Mc) {
  int k = blockIdx.x, n = threadIdx.x;  // block 192 threads
  float s = 0.f;
  if (n < 168) {
    for (int i = 0; i < 167; ++i) s += tbW[k * 167 + i] * bb[i * 168 + n];
  } else {
    int n2 = n - 168;
    for (int i = 0; i < 23; ++i) s += tfW[k * 23 + i] * bf[i * 24 + n2];
  }
  Mc[k * 192 + n] = s;
}

// ---------------- MFMA GEMM: [M x K] @ WT^T -> [M x NT*16] cols/blk -------
// WT is [256][Kpad] bf16, k-contiguous (pre-transposed, BN-folded).
// NCB col-blocks per 64-row tile: block covers cols [col0, col0+NT*16).
// A (bf16 path) and B staged via async global_load_lds width=16.
// Epilogue: + extra[col]; optional ReLU; optional *rsqrt(cur[row]) (GCN
// pre-scale — dinv computed inline from the degree array, no dinv pass);
// store bf16, or (SPLIT) fp32 split to backcast/forecast. STATS: fused BN.
// FILL: blocks past the gemm grid run the bucket-CSR fill for edges
// [eoff, eend) concurrently — 1 edge/thread (proven r7 config: fill is
// atomic-THROUGHPUT-bound, ILP doesn't help, and trailing blocks interleave
// with gemm instead of serializing in front of it). Fill is split across
// the two MLP gemms so each half hides under a compute window.
template <int NT, int NCB, bool AF32, bool RELU, bool SPLIT, bool DSCALE, bool STATS, bool FILL>
__global__ __launch_bounds__(256) void gemm_k(const void* __restrict__ Ap, int M, int Kpad,
                                              int lda, int Klim,
                                              const u16* __restrict__ WT,
                                              const float* __restrict__ extra,
                                              const int* __restrict__ curp,
                                              void* __restrict__ outp, float* __restrict__ out2,
                                              float* __restrict__ stout,
                                              const int* __restrict__ esrc,
                                              const int* __restrict__ edst,
                                              int* __restrict__ fcur, u16* __restrict__ fcsr,
                                              int eoff, int eend) {
  constexpr int BROWS = NT * 16;
  const int bid = (int)blockIdx.x;
  if constexpr (FILL) {
    int gemmblks = ((M + 63) / 64) * NCB;
    int fb = bid - gemmblks;
    if (fb >= 0) {   // block-uniform branch; returns before any __syncthreads
      int e = eoff + fb * 256 + (int)threadIdx.x;
      if (e < eend) {
        int d = edst[e];
        int p = atomicAdd(&fcur[d], 1);
        if (p < CAP) fcsr[(size_t)d * CAP + p] = (u16)esrc[e];
      }
      return;
    }
  }
  __shared__ __align__(16) u16 Alds[64][32];
  __shared__ __align__(16) u16 Blds[BROWS][32];
  constexpr int SR = STATS ? 4 : 1;
  constexpr int SC = STATS ? BROWS : 1;
  __shared__ float sred[SR][SC];
  __shared__ float qred[SR][SC];
  const int tid = threadIdx.x;
  const int wave = tid >> 6, lane = tid & 63;
  const int quad = lane >> 4, l16 = lane & 15;
  const int cb = bid % NCB;
  const int row0 = (bid / NCB) * 64;
  const int col0 = cb * BROWS;

  f32x4 acc[NT];
#pragma unroll
  for (int i = 0; i < NT; ++i) acc[i] = (f32x4){0.f, 0.f, 0.f, 0.f};

  const int am = tid >> 2;            // 0..63 tile row
  const int akc = (tid & 3) * 8;      // 0,8,16,24 k-chunk
  const int arow = row0 + am;

  for (int k0 = 0; k0 < Kpad; k0 += 32) {
    // --- stage A tile [64][32]: LDS flat offset = tid*16B (row-major) ---
    if constexpr (AF32) {
      uint4 pack = {0u, 0u, 0u, 0u};
      const float* A = (const float*)Ap;
      if (arow < M && (k0 + akc) < Klim) {
        const float* p = A + (size_t)arow * lda + k0 + akc;
        float4 fa = *(const float4*)p;
        float4 fb = *(const float4*)(p + 4);
        pack.x = (uint32_t)f2b(fa.x) | ((uint32_t)f2b(fa.y) << 16);
        pack.y = (uint32_t)f2b(fa.z) | ((uint32_t)f2b(fa.w) << 16);
        pack.z = (uint32_t)f2b(fb.x) | ((uint32_t)f2b(fb.y) << 16);
        pack.w = (uint32_t)f2b(fb.z) | ((uint32_t)f2b(fb.w) << 16);
      }
      *(uint4*)&Alds[am][akc] = pack;
    } else {
      const u16* A = (const u16*)Ap;
      if (arow < M)
        gl2lds16(A + (size_t)arow * lda + k0 + akc, &Alds[0][0] + (size_t)tid * 8);
      // rows >= M: stale LDS feeds only discarded acc rows
    }
    // --- stage B tile [BROWS][32]: issue i covers rows i*64+(tid>>2) ---
#pragma unroll
    for (int i = 0; i < (BROWS + 63) / 64; ++i) {
      int br = i * 64 + am;
      if (br < BROWS)
        gl2lds16(WT + (size_t)(col0 + br) * Kpad + k0 + akc,
                 &Blds[0][0] + (size_t)i * 2048 + (size_t)tid * 8);
    }
    __syncthreads();   // drains vmcnt -> LDS writes visible
    short8 av = *(const short8*)&Alds[wave * 16 + l16][quad * 8];
#pragma unroll
    for (int nt = 0; nt < NT; ++nt) {
      short8 bv = *(const short8*)&Blds[nt * 16 + l16][quad * 8];
      acc[nt] = __builtin_amdgcn_mfma_f32_16x16x32_bf16(av, bv, acc[nt], 0, 0, 0);
    }
    __syncthreads();
  }

  // --- epilogue: C/D layout col = lane&15, row = quad*4 + reg ---
#pragma unroll
  for (int nt = 0; nt < NT; ++nt) {
    float s = 0.f, q = 0.f;
    int col = col0 + nt * 16 + l16;
#pragma unroll
    for (int r = 0; r < 4; ++r) {
      int row = row0 + wave * 16 + quad * 4 + r;
      if (row >= M) continue;
      float v = acc[nt][r] + extra[col];
      if constexpr (RELU) v = fmaxf(v, 0.f);
      if constexpr (DSCALE) v *= rsqrtf((float)curp[row]);  // GCN pre-scale
      if constexpr (SPLIT) {
        if (col < 168) ((float*)outp)[(size_t)row * 168 + col] = v;
        else ((float*)out2)[(size_t)row * 24 + (col - 168)] = v;
      } else {
        ((u16*)outp)[(size_t)row * HD + col] = f2b(v);
      }
      if constexpr (STATS) { s += v; q += v * v; }
    }
    if constexpr (STATS) {
      // reduce over the wave's 16 rows (quads 0..3 share l16 -> same col)
      s += __shfl_xor(s, 16); s += __shfl_xor(s, 32);
      q += __shfl_xor(q, 16); q += __shfl_xor(q, 32);
      if (quad == 0) { sred[wave][nt * 16 + l16] = s; qred[wave][nt * 16 + l16] = q; }
    }
  }
  if constexpr (STATS) {
    __syncthreads();
    if (tid < BROWS) {
      float s = sred[0][tid] + sred[1][tid] + sred[2][tid] + sred[3][tid];
      float q = qred[0][tid] + qred[1][tid] + qred[2][tid] + qred[3][tid];
      int sl = (bid & 7) * 512;   // 8-way sliced accumulators
      atomicAdd(&stout[sl + col0 + tid], s);
      atomicAdd(&stout[sl + 256 + col0 + tid], q);
    }
  }
}

// ---------------- fold BN(stats,gamma,beta) into next weight ----------------
// stats arrive as 8 slices of [512] (sum | sumsq); sum the slices here.
__global__ __launch_bounds__(256) void fold_k(const float* __restrict__ st, float invM,
                                              const float* __restrict__ gamma,
                                              const float* __restrict__ beta,
                                              const float* __restrict__ W, int ncols,
                                              const float* __restrict__ bias,
                                              u16* __restrict__ WT, float* __restrict__ extra) {
  int n = blockIdx.x, k = threadIdx.x;
  float sm = 0.f, sq = 0.f;
#pragma unroll
  for (int s = 0; s < 8; ++s) { sm += st[s * 512 + k]; sq += st[s * 512 + 256 + k]; }
  float m = sm * invM;
  float v = sq * invM - m * m;
  float sc = gamma[k] * rsqrtf(v + EPSV);
  float sh = beta[k] - m * sc;
  float w = W[(size_t)k * ncols + n];
  WT[(size_t)n * HD + k] = f2b(sc * w);
  __shared__ float red[256];
  red[k] = sh * w;
  __syncthreads();
  for (int d = 128; d > 0; d >>= 1) {
    if (k < d) red[k] += red[k + d];
    __syncthreads();
  }
  if (k == 0) extra[n] = (bias ? bias[n] : 0.f) + red[0];
}

// ---------------- GCN aggregation: one wave per dst node ----------------
// xw rows are PRE-SCALED by dinv[src] in the gemm epilogue, so the inner
// loop is a pure gather-sum. 8-deep software pipeline to hide gather latency.
// BN stats fused into the epilogue. Bucket CSR (u16): node d's list is
// csr[d*CAP .. d*CAP+deg), deg = cur[d]; dinv computed inline as rsqrt(deg).
__global__ __launch_bounds__(256) void agg_k(const u16* __restrict__ csr,
                                             const int* __restrict__ deg,
                                             const u16* __restrict__ xw,
                                             const float* __restrict__ gb, u16* __restrict__ out,
                                             float* __restrict__ stout) {
  __shared__ float ss[4][256];
  __shared__ float qq[4][256];
  int wave = threadIdx.x >> 6, lane = threadIdx.x & 63;
  int dst = blockIdx.x * 4 + wave;
  bool valid = dst < NNODES;
  const int c = lane * 4;
  float r0 = 0.f, r1 = 0.f, r2 = 0.f, r3 = 0.f;
  if (valid) {
    int dv = min(deg[dst], CAP);
    int p0 = dst * CAP;
    int p1 = p0 + dv;
    float a0 = 0.f, a1 = 0.f, a2 = 0.f, a3 = 0.f;
    int p = p0;
#define ACCUM(vv)                              \
  a0 += b2f((u16)((vv).x & 0xffffu));          \
  a1 += b2f((u16)((vv).x >> 16));              \
  a2 += b2f((u16)((vv).y & 0xffffu));          \
  a3 += b2f((u16)((vv).y >> 16));
    for (; p + 8 <= p1; p += 8) {
      uint4 sw = *(const uint4*)&csr[p];   // 8 u16 indices
      int s0 = sw.x & 0xffff, s1 = sw.x >> 16;
      int s2 = sw.y & 0xffff, s3 = sw.y >> 16;
      int s4 = sw.z & 0xffff, s5 = sw.z >> 16;
      int s6 = sw.w & 0xffff, s7 = sw.w >> 16;
      uint2 v0 = *(const uint2*)&xw[(size_t)s0 * HD + c];
      uint2 v1 = *(const uint2*)&xw[(size_t)s1 * HD + c];
      uint2 v2 = *(const uint2*)&xw[(size_t)s2 * HD + c];
      uint2 v3 = *(const uint2*)&xw[(size_t)s3 * HD + c];
      uint2 v4 = *(const uint2*)&xw[(size_t)s4 * HD + c];
      uint2 v5 = *(const uint2*)&xw[(size_t)s5 * HD + c];
      uint2 v6 = *(const uint2*)&xw[(size_t)s6 * HD + c];
      uint2 v7 = *(const uint2*)&xw[(size_t)s7 * HD + c];
      ACCUM(v0); ACCUM(v1); ACCUM(v2); ACCUM(v3);
      ACCUM(v4); ACCUM(v5); ACCUM(v6); ACCUM(v7);
    }
    for (; p < p1; ++p) {
      int s = csr[p];
      uint2 v = *(const uint2*)&xw[(size_t)s * HD + c];
      ACCUM(v);
    }
#undef ACCUM
    float dd = rsqrtf((float)dv);
    float4 gv = *(const float4*)&gb[c];
    r0 = fmaxf(dd * a0 + gv.x, 0.f);
    r1 = fmaxf(dd * a1 + gv.y, 0.f);
    r2 = fmaxf(dd * a2 + gv.z, 0.f);
    r3 = fmaxf(dd * a3 + gv.w, 0.f);
    uint2 o;
    o.x = (uint32_t)f2b(r0) | ((uint32_t)f2b(r1) << 16);
    o.y = (uint32_t)f2b(r2) | ((uint32_t)f2b(r3) << 16);
    *(uint2*)&out[(size_t)dst * HD + c] = o;
  }
  // fused BN stats: reduce 4 waves' rows in LDS, one sliced atomic per col
  ss[wave][c + 0] = r0; ss[wave][c + 1] = r1; ss[wave][c + 2] = r2; ss[wave][c + 3] = r3;
  qq[wave][c + 0] = r0 * r0; qq[wave][c + 1] = r1 * r1;
  qq[wave][c + 2] = r2 * r2; qq[wave][c + 3] = r3 * r3;
  __syncthreads();
  int t = threadIdx.x;
  float s = ss[0][t] + ss[1][t] + ss[2][t] + ss[3][t];
  float q = qq[0][t] + qq[1][t] + qq[2][t] + qq[3][t];
  int sl = (blockIdx.x & 7) * 512;
  atomicAdd(&stout[sl + t], s);
  atomicAdd(&stout[sl + 256 + t], q);
}

// ---------------- launch ----------------

extern "C" void kernel_launch(void* const* d_in, const int* in_sizes, int n_in,
                              void* d_out, int out_size, void* d_ws, size_t ws_size,
                              hipStream_t stream) {
  const float* x = (const float*)d_in[0];
  const int* ei = (const int*)d_in[1];
  const float* w1 = (const float*)d_in[2];
  const float* b1 = (const float*)d_in[3];
  const float* g1 = (const float*)d_in[4];
  const float* bt1 = (const float*)d_in[5];
  const float* w2 = (const float*)d_in[6];
  const float* b2 = (const float*)d_in[7];
  const float* g2 = (const float*)d_in[8];
  const float* bt2 = (const float*)d_in[9];
  const float* gw1 = (const float*)d_in[10];
  const float* gb1 = (const float*)d_in[11];
  const float* gg1 = (const float*)d_in[12];
  const float* gbt1 = (const float*)d_in[13];
  const float* gw2 = (const float*)d_in[14];
  const float* gb2 = (const float*)d_in[15];
  const float* gg2 = (const float*)d_in[16];
  const float* gbt2 = (const float*)d_in[17];
  const float* tbW = (const float*)d_in[18];
  const float* tfW = (const float*)d_in[19];
  const float* bb = (const float*)d_in[20];
  const float* bfb = (const float*)d_in[21];
  const int* esrc = ei;
  const int* edst = ei + NEDGES;

  char* wsp = (char*)d_ws;
  size_t off = 0;
  auto alloc = [&](size_t b) {
    void* p = wsp + off;
    off += (b + 511) & ~(size_t)511;
    return p;
  };
  u16* buf1 = (u16*)alloc((size_t)NNODES * HD * 2);
  u16* buf2 = (u16*)alloc((size_t)NNODES * HD * 2);
  u16* csr = (u16*)alloc((size_t)NNODES * CAP * 2);
  int* cur = (int*)alloc((size_t)NNODES * 4);
  float* st = (float*)alloc((size_t)4 * 8 * 512 * 4);   // 4 sets x 8 slices x 512
  u16* W1T = (u16*)alloc(256 * 192 * 2);
  u16* WT = (u16*)alloc(256 * 256 * 2);
  float* Mc = (float*)alloc(256 * 192 * 4);
  float* extra = (float*)alloc(256 * 4);

  float* backc = (float*)d_out;
  float* forec = backc + (size_t)NNODES * 168;
  const float invM = 1.0f / (float)NNODES;

  const int GB = (NNODES + 63) / 64;  // 782
  const int HALF = NEDGES / 2;        // 800000 edges per fill half
  const int FB = HALF / 256;          // 3125 trailing fill blocks per gemm

  init_k<<<196, 256, 0, stream>>>(cur, csr, st);
  cw1_k<<<256, 192, 0, stream>>>(w1, W1T);
  mc_k<<<256, 192, 0, stream>>>(tbW, tfW, bb, bfb, Mc);

  // MLP layer 1 (stats fused) + fill of edges [0, 800K) in trailing blocks
  gemm_k<8, 2, true, true, false, false, true, true><<<GB * 2 + FB, 256, 0, stream>>>(
      x, NNODES, 192, 168, 168, W1T, b1, nullptr, buf1, nullptr, st,
      esrc, edst, cur, csr, 0, HALF);
  // fold BN1 into w2 (+b2)
  fold_k<<<256, 256, 0, stream>>>(st, invM, g1, bt1, w2, 256, b2, WT, extra);
  // MLP layer 2 (stats fused) + fill of edges [800K, 1.6M)
  gemm_k<8, 2, false, true, false, false, true, true><<<GB * 2 + FB, 256, 0, stream>>>(
      buf1, NNODES, 256, 256, 256, WT, extra, nullptr, buf2, nullptr, st + 4096,
      esrc, edst, cur, csr, HALF, NEDGES);
  // fold BN2 into gw1 (no bias: gb1 added after aggregation)
  fold_k<<<256, 256, 0, stream>>>(st + 4096, invM, g2, bt2, gw1, 256, nullptr, WT, extra);
  // xw1 = (BN2(a2)@gw1) * rsqrt(deg[row])  (fill complete: gemm2 kernel done)
  gemm_k<8, 2, false, false, false, true, false, false><<<GB * 2, 256, 0, stream>>>(
      buf2, NNODES, 256, 256, 256, WT, extra, cur, buf1, nullptr, nullptr,
      nullptr, nullptr, nullptr, nullptr, 0, 0);
  // g1a = ReLU(rsqrt(deg[dst]) * sum(xw1[src]) + gb1), stats fused
  agg_k<<<12500, 256, 0, stream>>>(csr, cur, buf1, gb1, buf2, st + 8192);
  // fold BN3 into gw2
  fold_k<<<256, 256, 0, stream>>>(st + 8192, invM, gg1, gbt1, gw2, 256, nullptr, WT, extra);
  // xw2 = (BN3(g1a)@gw2) * rsqrt(deg[row])
  gemm_k<8, 2, false, false, false, true, false, false><<<GB * 2, 256, 0, stream>>>(
      buf2, NNODES, 256, 256, 256, WT, extra, cur, buf1, nullptr, nullptr,
      nullptr, nullptr, nullptr, nullptr, 0, 0);
  // g2a = ReLU(rsqrt(deg[dst]) * sum(xw2[src]) + gb2), stats fused
  agg_k<<<12500, 256, 0, stream>>>(csr, cur, buf1, gb2, buf2, st + 12288);
  // fold BN4 into Mc [256][192]
  fold_k<<<192, 256, 0, stream>>>(st + 12288, invM, gg2, gbt2, Mc, 192, nullptr, WT, extra);
  // final: [backcast || forecast] = BN4(g2a) @ Mc (2 col-blocks of 96)
  gemm_k<6, 2, false, false, true, false, false, false><<<GB * 2, 256, 0, stream>>>(
      buf2, NNODES, 256, 256, 256, WT, extra, nullptr, backc, forec, nullptr,
      nullptr, nullptr, nullptr, nullptr, 0, 0);
}

// Round 11
// 591.667 us; speedup vs baseline: 1.0872x; 1.0303x over previous
//
#include <hip/hip_runtime.h>
#include <stdint.h>

#define NNODES 50000
#define NEDGES 1600000
#define HD 256
#define EPSV 1e-5f
#define CAP 80    // u16 bucket CSR stride; deg ~ Poisson(32), P(deg>=79) ~ 1e-11

typedef unsigned short u16;
typedef __attribute__((ext_vector_type(8))) short short8;
typedef __attribute__((ext_vector_type(4))) float f32x4;

__device__ __forceinline__ u16 f2b(float f) {
  union { float f; uint32_t u; } c; c.f = f;
  uint32_t u = c.u;
  u += 0x7fffu + ((u >> 16) & 1u);   // round-to-nearest-even
  return (u16)(u >> 16);
}
__device__ __forceinline__ float b2f(u16 s) {
  union { uint32_t u; float f; } c; c.u = ((uint32_t)s) << 16;
  return c.f;
}

// async 16B global -> LDS (direct-to-shared DMA). LDS dst must be
// wave-uniform base + lane*16 — our tid*16 flat mappings satisfy this.
__device__ __forceinline__ void gl2lds16(const u16* g, u16* l) {
  __builtin_amdgcn_global_load_lds(
      (__attribute__((address_space(1))) void*)(void*)g,
      (__attribute__((address_space(3))) void*)(void*)l, 16, 0, 0);
}

// ---------------- merged setup kernel ----------------
// blocks [0,196): cur/csr/st init (self-loop pre-seeded; cur doubles as
//                 fill cursor and degree). st: 4 sets x 8 slices x 512.
// blocks [196,452): w1 [168,256] fp32 -> W1T [256][192] bf16 (k-contig, pad)
// blocks [452,708): Mc [256][192] = [tbW@basis_b || tfW@basis_f]
__global__ void setup_k(int* __restrict__ cur, u16* __restrict__ csr, float* __restrict__ st,
                        const float* __restrict__ w1, u16* __restrict__ W1T,
                        const float* __restrict__ tbW, const float* __restrict__ tfW,
                        const float* __restrict__ bb, const float* __restrict__ bf,
                        float* __restrict__ Mc) {
  int b = blockIdx.x, t = threadIdx.x;
  if (b < 196) {
    int i = b * 256 + t;
    if (i < NNODES) { cur[i] = 1; csr[(size_t)i * CAP] = (u16)i; }
    if (i < 4 * 8 * 512) st[i] = 0.f;
  } else if (b < 452) {
    int n = b - 196;
    if (t < 192) W1T[n * 192 + t] = (t < 168) ? f2b(w1[t * HD + n]) : (u16)0;
  } else {
    int k = b - 452;
    if (t < 192) {
      float s = 0.f;
      if (t < 168) {
        for (int i = 0; i < 167; ++i) s += tbW[k * 167 + i] * bb[i * 168 + t];
      } else {
        int n2 = t - 168;
        for (int i = 0; i < 23; ++i) s += tfW[k * 23 + i] * bf[i * 24 + n2];
      }
      Mc[k * 192 + t] = s;
    }
  }
}

// ---------------- MFMA GEMM: [M x K] @ WT^T -> [M x NT*16] cols/blk -------
// WT is [256][Kpad] bf16, k-contiguous (pre-transposed, BN-folded).
// NCB col-blocks per 64-row tile: block covers cols [col0, col0+NT*16).
// BK=64 via TWO 32-wide K planes (Alds[2][64][32] / Blds[2][..][32]) —
// halves the __syncthreads/vmcnt-drain count (the ~20% structural stall)
// while keeping the 64B-row bank geometry (flat [64][64] would be a 16-way
// conflict, and padding breaks global_load_lds linear-dst).
// Epilogue: + extra[col]; optional ReLU; optional *rsqrt(cur[row]) (GCN
// pre-scale, computed inline — no dinv pass); store bf16, or (SPLIT) fp32
// split to backcast/forecast. STATS: fused BN sum/sumsq (sliced atomics).
// FILL: blocks past the gemm grid run the bucket-CSR fill for edges
// [eoff, eend), 1 edge/thread (fill is atomic-throughput-bound; trailing
// blocks interleave with the compute-bound gemm). Fill is split across the
// two MLP gemms so each half hides under a compute window.
template <int NT, int NCB, bool AF32, bool RELU, bool SPLIT, bool DSCALE, bool STATS, bool FILL>
__global__ __launch_bounds__(256) void gemm_k(const void* __restrict__ Ap, int M, int Kpad,
                                              int lda, int Klim,
                                              const u16* __restrict__ WT,
                                              const float* __restrict__ extra,
                                              const int* __restrict__ curp,
                                              void* __restrict__ outp, float* __restrict__ out2,
                                              float* __restrict__ stout,
                                              const int* __restrict__ esrc,
                                              const int* __restrict__ edst,
                                              int* __restrict__ fcur, u16* __restrict__ fcsr,
                                              int eoff, int eend) {
  constexpr int BROWS = NT * 16;
  const int bid = (int)blockIdx.x;
  if constexpr (FILL) {
    int gemmblks = ((M + 63) / 64) * NCB;
    int fb = bid - gemmblks;
    if (fb >= 0) {   // block-uniform branch; returns before any __syncthreads
      int e = eoff + fb * 256 + (int)threadIdx.x;
      if (e < eend) {
        int d = edst[e];
        int p = atomicAdd(&fcur[d], 1);
        if (p < CAP) fcsr[(size_t)d * CAP + p] = (u16)esrc[e];
      }
      return;
    }
  }
  __shared__ __align__(16) u16 Alds[2][64][32];
  __shared__ __align__(16) u16 Blds[2][BROWS][32];
  constexpr int SR = STATS ? 4 : 1;
  constexpr int SC = STATS ? BROWS : 1;
  __shared__ float sred[SR][SC];
  __shared__ float qred[SR][SC];
  const int tid = threadIdx.x;
  const int wave = tid >> 6, lane = tid & 63;
  const int quad = lane >> 4, l16 = lane & 15;
  const int cb = bid % NCB;
  const int row0 = (bid / NCB) * 64;
  const int col0 = cb * BROWS;

  f32x4 acc[NT];
#pragma unroll
  for (int i = 0; i < NT; ++i) acc[i] = (f32x4){0.f, 0.f, 0.f, 0.f};

  const int am = tid >> 2;            // 0..63 tile row
  const int akc = (tid & 3) * 8;      // 0,8,16,24 k-chunk within a plane
  const int arow = row0 + am;

  for (int k0 = 0; k0 < Kpad; k0 += 64) {
    // --- stage A planes [2][64][32]: LDS flat offset = tid*16B per plane ---
    if constexpr (AF32) {
      const float* A = (const float*)Ap;
#pragma unroll
      for (int p = 0; p < 2; ++p) {
        uint4 pack = {0u, 0u, 0u, 0u};
        int kk = k0 + p * 32 + akc;
        if (arow < M && kk < Klim) {
          const float* pp = A + (size_t)arow * lda + kk;
          float4 fa = *(const float4*)pp;
          float4 fb = *(const float4*)(pp + 4);
          pack.x = (uint32_t)f2b(fa.x) | ((uint32_t)f2b(fa.y) << 16);
          pack.y = (uint32_t)f2b(fa.z) | ((uint32_t)f2b(fa.w) << 16);
          pack.z = (uint32_t)f2b(fb.x) | ((uint32_t)f2b(fb.y) << 16);
          pack.w = (uint32_t)f2b(fb.z) | ((uint32_t)f2b(fb.w) << 16);
        }
        *(uint4*)(&Alds[p][0][0] + (size_t)tid * 8) = pack;
      }
    } else {
      const u16* A = (const u16*)Ap;
      if (arow < M) {
        gl2lds16(A + (size_t)arow * lda + k0 + akc, &Alds[0][0][0] + (size_t)tid * 8);
        gl2lds16(A + (size_t)arow * lda + k0 + 32 + akc, &Alds[1][0][0] + (size_t)tid * 8);
      }
      // rows >= M: stale LDS feeds only discarded acc rows
    }
    // --- stage B planes: issue (p,j) covers rows j*64+am of plane p ---
#pragma unroll
    for (int p = 0; p < 2; ++p) {
#pragma unroll
      for (int j = 0; j < (BROWS + 63) / 64; ++j) {
        int br = j * 64 + am;
        if (br < BROWS)   // wave-uniform (BROWS multiple of 16)
          gl2lds16(WT + (size_t)(col0 + br) * Kpad + k0 + p * 32 + akc,
                   &Blds[p][0][0] + (size_t)j * 2048 + (size_t)tid * 8);
      }
    }
    __syncthreads();   // drains vmcnt -> LDS writes visible
    short8 av0 = *(const short8*)&Alds[0][wave * 16 + l16][quad * 8];
    short8 av1 = *(const short8*)&Alds[1][wave * 16 + l16][quad * 8];
#pragma unroll
    for (int nt = 0; nt < NT; ++nt) {
      short8 bv0 = *(const short8*)&Blds[0][nt * 16 + l16][quad * 8];
      short8 bv1 = *(const short8*)&Blds[1][nt * 16 + l16][quad * 8];
      acc[nt] = __builtin_amdgcn_mfma_f32_16x16x32_bf16(av0, bv0, acc[nt], 0, 0, 0);
      acc[nt] = __builtin_amdgcn_mfma_f32_16x16x32_bf16(av1, bv1, acc[nt], 0, 0, 0);
    }
    __syncthreads();
  }

  // --- epilogue: C/D layout col = lane&15, row = quad*4 + reg ---
#pragma unroll
  for (int nt = 0; nt < NT; ++nt) {
    float s = 0.f, q = 0.f;
    int col = col0 + nt * 16 + l16;
#pragma unroll
    for (int r = 0; r < 4; ++r) {
      int row = row0 + wave * 16 + quad * 4 + r;
      if (row >= M) continue;
      float v = acc[nt][r] + extra[col];
      if constexpr (RELU) v = fmaxf(v, 0.f);
      if constexpr (DSCALE) v *= rsqrtf((float)curp[row]);  // GCN pre-scale
      if constexpr (SPLIT) {
        if (col < 168) ((float*)outp)[(size_t)row * 168 + col] = v;
        else ((float*)out2)[(size_t)row * 24 + (col - 168)] = v;
      } else {
        ((u16*)outp)[(size_t)row * HD + col] = f2b(v);
      }
      if constexpr (STATS) { s += v; q += v * v; }
    }
    if constexpr (STATS) {
      // reduce over the wave's 16 rows (quads 0..3 share l16 -> same col)
      s += __shfl_xor(s, 16); s += __shfl_xor(s, 32);
      q += __shfl_xor(q, 16); q += __shfl_xor(q, 32);
      if (quad == 0) { sred[wave][nt * 16 + l16] = s; qred[wave][nt * 16 + l16] = q; }
    }
  }
  if constexpr (STATS) {
    __syncthreads();
    if (tid < BROWS) {
      float s = sred[0][tid] + sred[1][tid] + sred[2][tid] + sred[3][tid];
      float q = qred[0][tid] + qred[1][tid] + qred[2][tid] + qred[3][tid];
      int sl = (bid & 7) * 512;   // 8-way sliced accumulators
      atomicAdd(&stout[sl + col0 + tid], s);
      atomicAdd(&stout[sl + 256 + col0 + tid], q);
    }
  }
}

// ---------------- fold BN(stats,gamma,beta) into next weight ----------------
// stats arrive as 8 slices of [512] (sum | sumsq); sum the slices here.
__global__ __launch_bounds__(256) void fold_k(const float* __restrict__ st, float invM,
                                              const float* __restrict__ gamma,
                                              const float* __restrict__ beta,
                                              const float* __restrict__ W, int ncols,
                                              const float* __restrict__ bias,
                                              u16* __restrict__ WT, float* __restrict__ extra) {
  int n = blockIdx.x, k = threadIdx.x;
  float sm = 0.f, sq = 0.f;
#pragma unroll
  for (int s = 0; s < 8; ++s) { sm += st[s * 512 + k]; sq += st[s * 512 + 256 + k]; }
  float m = sm * invM;
  float v = sq * invM - m * m;
  float sc = gamma[k] * rsqrtf(v + EPSV);
  float sh = beta[k] - m * sc;
  float w = W[(size_t)k * ncols + n];
  WT[(size_t)n * HD + k] = f2b(sc * w);
  __shared__ float red[256];
  red[k] = sh * w;
  __syncthreads();
  for (int d = 128; d > 0; d >>= 1) {
    if (k < d) red[k] += red[k + d];
    __syncthreads();
  }
  if (k == 0) extra[n] = (bias ? bias[n] : 0.f) + red[0];
}

// ---------------- GCN aggregation: one wave per dst node ----------------
// xw rows are PRE-SCALED by dinv[src] in the gemm epilogue, so the inner
// loop is a pure gather-sum. 8-deep software pipeline to hide gather latency.
// BN stats fused into the epilogue. Bucket CSR (u16): node d's list is
// csr[d*CAP .. d*CAP+deg), deg = cur[d]; dinv computed inline as rsqrt(deg).
__global__ __launch_bounds__(256) void agg_k(const u16* __restrict__ csr,
                                             const int* __restrict__ deg,
                                             const u16* __restrict__ xw,
                                             const float* __restrict__ gb, u16* __restrict__ out,
                                             float* __restrict__ stout) {
  __shared__ float ss[4][256];
  __shared__ float qq[4][256];
  int wave = threadIdx.x >> 6, lane = threadIdx.x & 63;
  int dst = blockIdx.x * 4 + wave;
  bool valid = dst < NNODES;
  const int c = lane * 4;
  float r0 = 0.f, r1 = 0.f, r2 = 0.f, r3 = 0.f;
  if (valid) {
    int dv = min(deg[dst], CAP);
    int p0 = dst * CAP;
    int p1 = p0 + dv;
    float a0 = 0.f, a1 = 0.f, a2 = 0.f, a3 = 0.f;
    int p = p0;
#define ACCUM(vv)                              \
  a0 += b2f((u16)((vv).x & 0xffffu));          \
  a1 += b2f((u16)((vv).x >> 16));              \
  a2 += b2f((u16)((vv).y & 0xffffu));          \
  a3 += b2f((u16)((vv).y >> 16));
    for (; p + 8 <= p1; p += 8) {
      uint4 sw = *(const uint4*)&csr[p];   // 8 u16 indices
      int s0 = sw.x & 0xffff, s1 = sw.x >> 16;
      int s2 = sw.y & 0xffff, s3 = sw.y >> 16;
      int s4 = sw.z & 0xffff, s5 = sw.z >> 16;
      int s6 = sw.w & 0xffff, s7 = sw.w >> 16;
      uint2 v0 = *(const uint2*)&xw[(size_t)s0 * HD + c];
      uint2 v1 = *(const uint2*)&xw[(size_t)s1 * HD + c];
      uint2 v2 = *(const uint2*)&xw[(size_t)s2 * HD + c];
      uint2 v3 = *(const uint2*)&xw[(size_t)s3 * HD + c];
      uint2 v4 = *(const uint2*)&xw[(size_t)s4 * HD + c];
      uint2 v5 = *(const uint2*)&xw[(size_t)s5 * HD + c];
      uint2 v6 = *(const uint2*)&xw[(size_t)s6 * HD + c];
      uint2 v7 = *(const uint2*)&xw[(size_t)s7 * HD + c];
      ACCUM(v0); ACCUM(v1); ACCUM(v2); ACCUM(v3);
      ACCUM(v4); ACCUM(v5); ACCUM(v6); ACCUM(v7);
    }
    for (; p < p1; ++p) {
      int s = csr[p];
      uint2 v = *(const uint2*)&xw[(size_t)s * HD + c];
      ACCUM(v);
    }
#undef ACCUM
    float dd = rsqrtf((float)dv);
    float4 gv = *(const float4*)&gb[c];
    r0 = fmaxf(dd * a0 + gv.x, 0.f);
    r1 = fmaxf(dd * a1 + gv.y, 0.f);
    r2 = fmaxf(dd * a2 + gv.z, 0.f);
    r3 = fmaxf(dd * a3 + gv.w, 0.f);
    uint2 o;
    o.x = (uint32_t)f2b(r0) | ((uint32_t)f2b(r1) << 16);
    o.y = (uint32_t)f2b(r2) | ((uint32_t)f2b(r3) << 16);
    *(uint2*)&out[(size_t)dst * HD + c] = o;
  }
  // fused BN stats: reduce 4 waves' rows in LDS, one sliced atomic per col
  ss[wave][c + 0] = r0; ss[wave][c + 1] = r1; ss[wave][c + 2] = r2; ss[wave][c + 3] = r3;
  qq[wave][c + 0] = r0 * r0; qq[wave][c + 1] = r1 * r1;
  qq[wave][c + 2] = r2 * r2; qq[wave][c + 3] = r3 * r3;
  __syncthreads();
  int t = threadIdx.x;
  float s = ss[0][t] + ss[1][t] + ss[2][t] + ss[3][t];
  float q = qq[0][t] + qq[1][t] + qq[2][t] + qq[3][t];
  int sl = (blockIdx.x & 7) * 512;
  atomicAdd(&stout[sl + t], s);
  atomicAdd(&stout[sl + 256 + t], q);
}

// ---------------- launch ----------------

extern "C" void kernel_launch(void* const* d_in, const int* in_sizes, int n_in,
                              void* d_out, int out_size, void* d_ws, size_t ws_size,
                              hipStream_t stream) {
  const float* x = (const float*)d_in[0];
  const int* ei = (const int*)d_in[1];
  const float* w1 = (const float*)d_in[2];
  const float* b1 = (const float*)d_in[3];
  const float* g1 = (const float*)d_in[4];
  const float* bt1 = (const float*)d_in[5];
  const float* w2 = (const float*)d_in[6];
  const float* b2 = (const float*)d_in[7];
  const float* g2 = (const float*)d_in[8];
  const float* bt2 = (const float*)d_in[9];
  const float* gw1 = (const float*)d_in[10];
  const float* gb1 = (const float*)d_in[11];
  const float* gg1 = (const float*)d_in[12];
  const float* gbt1 = (const float*)d_in[13];
  const float* gw2 = (const float*)d_in[14];
  const float* gb2 = (const float*)d_in[15];
  const float* gg2 = (const float*)d_in[16];
  const float* gbt2 = (const float*)d_in[17];
  const float* tbW = (const float*)d_in[18];
  const float* tfW = (const float*)d_in[19];
  const float* bb = (const float*)d_in[20];
  const float* bfb = (const float*)d_in[21];
  const int* esrc = ei;
  const int* edst = ei + NEDGES;

  char* wsp = (char*)d_ws;
  size_t off = 0;
  auto alloc = [&](size_t b) {
    void* p = wsp + off;
    off += (b + 511) & ~(size_t)511;
    return p;
  };
  u16* buf1 = (u16*)alloc((size_t)NNODES * HD * 2);
  u16* buf2 = (u16*)alloc((size_t)NNODES * HD * 2);
  u16* csr = (u16*)alloc((size_t)NNODES * CAP * 2);
  int* cur = (int*)alloc((size_t)NNODES * 4);
  float* st = (float*)alloc((size_t)4 * 8 * 512 * 4);   // 4 sets x 8 slices x 512
  u16* W1T = (u16*)alloc(256 * 192 * 2);
  u16* WT = (u16*)alloc(256 * 256 * 2);
  float* Mc = (float*)alloc(256 * 192 * 4);
  float* extra = (float*)alloc(256 * 4);

  float* backc = (float*)d_out;
  float* forec = backc + (size_t)NNODES * 168;
  const float invM = 1.0f / (float)NNODES;

  const int GB = (NNODES + 63) / 64;  // 782
  const int HALF = NEDGES / 2;        // 800000 edges per fill half
  const int FB = HALF / 256;          // 3125 trailing fill blocks per gemm

  setup_k<<<708, 256, 0, stream>>>(cur, csr, st, w1, W1T, tbW, tfW, bb, bfb, Mc);

  // MLP layer 1 (stats fused) + fill of edges [0, 800K) in trailing blocks
  gemm_k<8, 2, true, true, false, false, true, true><<<GB * 2 + FB, 256, 0, stream>>>(
      x, NNODES, 192, 168, 168, W1T, b1, nullptr, buf1, nullptr, st,
      esrc, edst, cur, csr, 0, HALF);
  // fold BN1 into w2 (+b2)
  fold_k<<<256, 256, 0, stream>>>(st, invM, g1, bt1, w2, 256, b2, WT, extra);
  // MLP layer 2 (stats fused) + fill of edges [800K, 1.6M)
  gemm_k<8, 2, false, true, false, false, true, true><<<GB * 2 + FB, 256, 0, stream>>>(
      buf1, NNODES, 256, 256, 256, WT, extra, nullptr, buf2, nullptr, st + 4096,
      esrc, edst, cur, csr, HALF, NEDGES);
  // fold BN2 into gw1 (no bias: gb1 added after aggregation)
  fold_k<<<256, 256, 0, stream>>>(st + 4096, invM, g2, bt2, gw1, 256, nullptr, WT, extra);
  // xw1 = (BN2(a2)@gw1) * rsqrt(deg[row])  (fill complete: gemm2 kernel done)
  gemm_k<8, 2, false, false, false, true, false, false><<<GB * 2, 256, 0, stream>>>(
      buf2, NNODES, 256, 256, 256, WT, extra, cur, buf1, nullptr, nullptr,
      nullptr, nullptr, nullptr, nullptr, 0, 0);
  // g1a = ReLU(rsqrt(deg[dst]) * sum(xw1[src]) + gb1), stats fused
  agg_k<<<12500, 256, 0, stream>>>(csr, cur, buf1, gb1, buf2, st + 8192);
  // fold BN3 into gw2
  fold_k<<<256, 256, 0, stream>>>(st + 8192, invM, gg1, gbt1, gw2, 256, nullptr, WT, extra);
  // xw2 = (BN3(g1a)@gw2) * rsqrt(deg[row])
  gemm_k<8, 2, false, false, false, true, false, false><<<GB * 2, 256, 0, stream>>>(
      buf2, NNODES, 256, 256, 256, WT, extra, cur, buf1, nullptr, nullptr,
      nullptr, nullptr, nullptr, nullptr, 0, 0);
  // g2a = ReLU(rsqrt(deg[dst]) * sum(xw2[src]) + gb2), stats fused
  agg_k<<<12500, 256, 0, stream>>>(csr, cur, buf1, gb2, buf2, st + 12288);
  // fold BN4 into Mc [256][192]
  fold_k<<<192, 256, 0, stream>>>(st + 12288, invM, gg2, gbt2, Mc, 192, nullptr, WT, extra);
  // final: [backcast || forecast] = BN4(g2a) @ Mc (2 col-blocks of 96)
  gemm_k<6, 2, false, false, true, false, false, false><<<GB * 2, 256, 0, stream>>>(
      buf2, NNODES, 256, 256, 256, WT, extra, nullptr, backc, forec, nullptr,
      nullptr, nullptr, nullptr, nullptr, 0, 0);
}

// Round 13
// 574.958 us; speedup vs baseline: 1.1188x; 1.0291x over previous
//
#include <hip/hip_runtime.h>
#include <stdint.h>

#define NNODES 50000
#define NEDGES 1600000
#define HD 256
#define EPSV 1e-5f
#define CAP 80    // u16 bucket CSR stride; deg ~ Poisson(32), P(deg>=79) ~ 1e-11

typedef unsigned short u16;
typedef __attribute__((ext_vector_type(8))) short short8;
typedef __attribute__((ext_vector_type(4))) float f32x4;

__device__ __forceinline__ u16 f2b(float f) {
  union { float f; uint32_t u; } c; c.f = f;
  uint32_t u = c.u;
  u += 0x7fffu + ((u >> 16) & 1u);   // round-to-nearest-even
  return (u16)(u >> 16);
}
__device__ __forceinline__ float b2f(u16 s) {
  union { uint32_t u; float f; } c; c.u = ((uint32_t)s) << 16;
  return c.f;
}

// async 16B global -> LDS (direct-to-shared DMA). LDS dst must be
// wave-uniform base + lane*16 — our tid*16 flat mappings satisfy this.
__device__ __forceinline__ void gl2lds16(const u16* g, u16* l) {
  __builtin_amdgcn_global_load_lds(
      (__attribute__((address_space(1))) void*)(void*)g,
      (__attribute__((address_space(3))) void*)(void*)l, 16, 0, 0);
}

// ---------------- merged setup kernel ----------------
// blocks [0,196): cur/csr/st init (self-loop pre-seeded; cur doubles as
//                 fill cursor and degree). st: 4 sets x 8 slices x 512.
// blocks [196,452): w1 [168,256] fp32 -> W1T [256][192] bf16 (k-contig, pad)
// blocks [452,708): Mc [256][192] = [tbW@basis_b || tfW@basis_f]
__global__ void setup_k(int* __restrict__ cur, u16* __restrict__ csr, float* __restrict__ st,
                        const float* __restrict__ w1, u16* __restrict__ W1T,
                        const float* __restrict__ tbW, const float* __restrict__ tfW,
                        const float* __restrict__ bb, const float* __restrict__ bf,
                        float* __restrict__ Mc) {
  int b = blockIdx.x, t = threadIdx.x;
  if (b < 196) {
    int i = b * 256 + t;
    if (i < NNODES) { cur[i] = 1; csr[(size_t)i * CAP] = (u16)i; }
    if (i < 4 * 8 * 512) st[i] = 0.f;
  } else if (b < 452) {
    int n = b - 196;
    if (t < 192) W1T[n * 192 + t] = (t < 168) ? f2b(w1[t * HD + n]) : (u16)0;
  } else {
    int k = b - 452;
    if (t < 192) {
      float s = 0.f;
      if (t < 168) {
        for (int i = 0; i < 167; ++i) s += tbW[k * 167 + i] * bb[i * 168 + t];
      } else {
        int n2 = t - 168;
        for (int i = 0; i < 23; ++i) s += tfW[k * 23 + i] * bf[i * 24 + n2];
      }
      Mc[k * 192 + t] = s;
    }
  }
}

// ---------------- MFMA GEMM: [M x K] @ WT^T -> [M x NT*16] cols/blk -------
// WT is [256][Kpad] bf16, k-contiguous (pre-transposed, BN-folded).
// NCB col-blocks per 64-row tile: block covers cols [col0, col0+NT*16).
// BK=64 via TWO 32-wide K planes (Alds[2][64][32] / Blds[2][..][32]) —
// halves the __syncthreads/vmcnt-drain count while keeping the 64B-row
// bank geometry (flat [64][64] would be 16-way conflicted; padding breaks
// global_load_lds linear-dst).
// Epilogue: + extra[col]; optional ReLU; optional *rsqrt(cur[row]) (GCN
// pre-scale); store bf16, or (SPLIT) fp32 split to backcast/forecast.
// STATS: fused BN sum/sumsq (sliced atomics).
// FILL: blocks past the gemm grid run the bucket-CSR fill for edges
// [eoff, eend), 1 edge/thread (fill is atomic-throughput-bound; trailing
// blocks interleave with the compute-bound gemm). Fill is split in thirds
// under gemm1 / gemm2 / xw1-gemm — xw1 writes UNSCALED xw (DSCALE off) so
// its epilogue never reads cur while fill still increments it; agg1
// applies the per-src scale instead.
template <int NT, int NCB, bool AF32, bool RELU, bool SPLIT, bool DSCALE, bool STATS, bool FILL>
__global__ __launch_bounds__(256) void gemm_k(const void* __restrict__ Ap, int M, int Kpad,
                                              int lda, int Klim,
                                              const u16* __restrict__ WT,
                                              const float* __restrict__ extra,
                                              const int* __restrict__ curp,
                                              void* __restrict__ outp, float* __restrict__ out2,
                                              float* __restrict__ stout,
                                              const int* __restrict__ esrc,
                                              const int* __restrict__ edst,
                                              int* __restrict__ fcur, u16* __restrict__ fcsr,
                                              int eoff, int eend) {
  constexpr int BROWS = NT * 16;
  const int bid = (int)blockIdx.x;
  if constexpr (FILL) {
    int gemmblks = ((M + 63) / 64) * NCB;
    int fb = bid - gemmblks;
    if (fb >= 0) {   // block-uniform branch; returns before any __syncthreads
      int e = eoff + fb * 256 + (int)threadIdx.x;
      if (e < eend) {
        int d = edst[e];
        int p = atomicAdd(&fcur[d], 1);
        if (p < CAP) fcsr[(size_t)d * CAP + p] = (u16)esrc[e];
      }
      return;
    }
  }
  __shared__ __align__(16) u16 Alds[2][64][32];
  __shared__ __align__(16) u16 Blds[2][BROWS][32];
  constexpr int SR = STATS ? 4 : 1;
  constexpr int SC = STATS ? BROWS : 1;
  __shared__ float sred[SR][SC];
  __shared__ float qred[SR][SC];
  const int tid = threadIdx.x;
  const int wave = tid >> 6, lane = tid & 63;
  const int quad = lane >> 4, l16 = lane & 15;
  const int cb = bid % NCB;
  const int row0 = (bid / NCB) * 64;
  const int col0 = cb * BROWS;

  f32x4 acc[NT];
#pragma unroll
  for (int i = 0; i < NT; ++i) acc[i] = (f32x4){0.f, 0.f, 0.f, 0.f};

  const int am = tid >> 2;            // 0..63 tile row
  const int akc = (tid & 3) * 8;      // 0,8,16,24 k-chunk within a plane
  const int arow = row0 + am;

  for (int k0 = 0; k0 < Kpad; k0 += 64) {
    // --- stage A planes [2][64][32]: LDS flat offset = tid*16B per plane ---
    if constexpr (AF32) {
      const float* A = (const float*)Ap;
#pragma unroll
      for (int p = 0; p < 2; ++p) {
        uint4 pack = {0u, 0u, 0u, 0u};
        int kk = k0 + p * 32 + akc;
        if (arow < M && kk < Klim) {
          const float* pp = A + (size_t)arow * lda + kk;
          float4 fa = *(const float4*)pp;
          float4 fb = *(const float4*)(pp + 4);
          pack.x = (uint32_t)f2b(fa.x) | ((uint32_t)f2b(fa.y) << 16);
          pack.y = (uint32_t)f2b(fa.z) | ((uint32_t)f2b(fa.w) << 16);
          pack.z = (uint32_t)f2b(fb.x) | ((uint32_t)f2b(fb.y) << 16);
          pack.w = (uint32_t)f2b(fb.z) | ((uint32_t)f2b(fb.w) << 16);
        }
        *(uint4*)(&Alds[p][0][0] + (size_t)tid * 8) = pack;
      }
    } else {
      const u16* A = (const u16*)Ap;
      if (arow < M) {
        gl2lds16(A + (size_t)arow * lda + k0 + akc, &Alds[0][0][0] + (size_t)tid * 8);
        gl2lds16(A + (size_t)arow * lda + k0 + 32 + akc, &Alds[1][0][0] + (size_t)tid * 8);
      }
      // rows >= M: stale LDS feeds only discarded acc rows
    }
    // --- stage B planes: issue (p,j) covers rows j*64+am of plane p ---
#pragma unroll
    for (int p = 0; p < 2; ++p) {
#pragma unroll
      for (int j = 0; j < (BROWS + 63) / 64; ++j) {
        int br = j * 64 + am;
        if (br < BROWS)   // wave-uniform (BROWS multiple of 16)
          gl2lds16(WT + (size_t)(col0 + br) * Kpad + k0 + p * 32 + akc,
                   &Blds[p][0][0] + (size_t)j * 2048 + (size_t)tid * 8);
      }
    }
    __syncthreads();   // drains vmcnt -> LDS writes visible
    short8 av0 = *(const short8*)&Alds[0][wave * 16 + l16][quad * 8];
    short8 av1 = *(const short8*)&Alds[1][wave * 16 + l16][quad * 8];
#pragma unroll
    for (int nt = 0; nt < NT; ++nt) {
      short8 bv0 = *(const short8*)&Blds[0][nt * 16 + l16][quad * 8];
      short8 bv1 = *(const short8*)&Blds[1][nt * 16 + l16][quad * 8];
      acc[nt] = __builtin_amdgcn_mfma_f32_16x16x32_bf16(av0, bv0, acc[nt], 0, 0, 0);
      acc[nt] = __builtin_amdgcn_mfma_f32_16x16x32_bf16(av1, bv1, acc[nt], 0, 0, 0);
    }
    __syncthreads();
  }

  // --- epilogue: C/D layout col = lane&15, row = quad*4 + reg ---
#pragma unroll
  for (int nt = 0; nt < NT; ++nt) {
    float s = 0.f, q = 0.f;
    int col = col0 + nt * 16 + l16;
#pragma unroll
    for (int r = 0; r < 4; ++r) {
      int row = row0 + wave * 16 + quad * 4 + r;
      if (row >= M) continue;
      float v = acc[nt][r] + extra[col];
      if constexpr (RELU) v = fmaxf(v, 0.f);
      if constexpr (DSCALE) v *= rsqrtf((float)curp[row]);  // GCN pre-scale
      if constexpr (SPLIT) {
        if (col < 168) ((float*)outp)[(size_t)row * 168 + col] = v;
        else ((float*)out2)[(size_t)row * 24 + (col - 168)] = v;
      } else {
        ((u16*)outp)[(size_t)row * HD + col] = f2b(v);
      }
      if constexpr (STATS) { s += v; q += v * v; }
    }
    if constexpr (STATS) {
      // reduce over the wave's 16 rows (quads 0..3 share l16 -> same col)
      s += __shfl_xor(s, 16); s += __shfl_xor(s, 32);
      q += __shfl_xor(q, 16); q += __shfl_xor(q, 32);
      if (quad == 0) { sred[wave][nt * 16 + l16] = s; qred[wave][nt * 16 + l16] = q; }
    }
  }
  if constexpr (STATS) {
    __syncthreads();
    if (tid < BROWS) {
      float s = sred[0][tid] + sred[1][tid] + sred[2][tid] + sred[3][tid];
      float q = qred[0][tid] + qred[1][tid] + qred[2][tid] + qred[3][tid];
      int sl = (bid & 7) * 512;   // 8-way sliced accumulators
      atomicAdd(&stout[sl + col0 + tid], s);
      atomicAdd(&stout[sl + 256 + col0 + tid], q);
    }
  }
}

// ---------------- fold BN(stats,gamma,beta) into next weight ----------------
// stats arrive as 8 slices of [512] (sum | sumsq); sum the slices here.
__global__ __launch_bounds__(256) void fold_k(const float* __restrict__ st, float invM,
                                              const float* __restrict__ gamma,
                                              const float* __restrict__ beta,
                                              const float* __restrict__ W, int ncols,
                                              const float* __restrict__ bias,
                                              u16* __restrict__ WT, float* __restrict__ extra) {
  int n = blockIdx.x, k = threadIdx.x;
  float sm = 0.f, sq = 0.f;
#pragma unroll
  for (int s = 0; s < 8; ++s) { sm += st[s * 512 + k]; sq += st[s * 512 + 256 + k]; }
  float m = sm * invM;
  float v = sq * invM - m * m;
  float sc = gamma[k] * rsqrtf(v + EPSV);
  float sh = beta[k] - m * sc;
  float w = W[(size_t)k * ncols + n];
  WT[(size_t)n * HD + k] = f2b(sc * w);
  __shared__ float red[256];
  red[k] = sh * w;
  __syncthreads();
  for (int d = 128; d > 0; d >>= 1) {
    if (k < d) red[k] += red[k + d];
    __syncthreads();
  }
  if (k == 0) extra[n] = (bias ? bias[n] : 0.f) + red[0];
}

// ---------------- GCN aggregation: one wave per dst node ----------------
// Bucket CSR (u16): node d's list is csr[d*CAP .. d*CAP+deg), deg = cur[d].
// SRCSCALE=false: xw rows arrive PRE-SCALED by dinv[src] (gemm epilogue) —
// pure gather-sum. SRCSCALE=true: xw is UNSCALED (its producer overlapped
// the CSR fill, so it couldn't read cur); scale each gathered row by
// rsqrt(deg[src]) inline — deg is 200KB, L2-resident, per-edge address is
// wave-uniform (broadcast load); rsqrt rides the 70% idle VALU.
// BN stats fused into the epilogue (sliced atomics).
template <bool SRCSCALE>
__global__ __launch_bounds__(256) void agg_k(const u16* __restrict__ csr,
                                             const int* __restrict__ deg,
                                             const u16* __restrict__ xw,
                                             const float* __restrict__ gb, u16* __restrict__ out,
                                             float* __restrict__ stout) {
  __shared__ float ss[4][256];
  __shared__ float qq[4][256];
  int wave = threadIdx.x >> 6, lane = threadIdx.x & 63;
  int dst = blockIdx.x * 4 + wave;
  bool valid = dst < NNODES;
  const int c = lane * 4;
  float r0 = 0.f, r1 = 0.f, r2 = 0.f, r3 = 0.f;
  if (valid) {
    int dv = min(deg[dst], CAP);
    int p0 = dst * CAP;
    int p1 = p0 + dv;
    float a0 = 0.f, a1 = 0.f, a2 = 0.f, a3 = 0.f;
    int p = p0;
#define ACCUMS(vv, dd)                               \
  a0 += (dd) * b2f((u16)((vv).x & 0xffffu));         \
  a1 += (dd) * b2f((u16)((vv).x >> 16));             \
  a2 += (dd) * b2f((u16)((vv).y & 0xffffu));         \
  a3 += (dd) * b2f((u16)((vv).y >> 16));
    for (; p + 8 <= p1; p += 8) {
      uint4 sw = *(const uint4*)&csr[p];   // 8 u16 indices (wave-uniform)
      int s0 = sw.x & 0xffff, s1 = sw.x >> 16;
      int s2 = sw.y & 0xffff, s3 = sw.y >> 16;
      int s4 = sw.z & 0xffff, s5 = sw.z >> 16;
      int s6 = sw.w & 0xffff, s7 = sw.w >> 16;
      float d0 = 1.f, d1 = 1.f, d2 = 1.f, d3 = 1.f;
      float d4 = 1.f, d5 = 1.f, d6 = 1.f, d7 = 1.f;
      if constexpr (SRCSCALE) {
        d0 = rsqrtf((float)deg[s0]); d1 = rsqrtf((float)deg[s1]);
        d2 = rsqrtf((float)deg[s2]); d3 = rsqrtf((float)deg[s3]);
        d4 = rsqrtf((float)deg[s4]); d5 = rsqrtf((float)deg[s5]);
        d6 = rsqrtf((float)deg[s6]); d7 = rsqrtf((float)deg[s7]);
      }
      uint2 v0 = *(const uint2*)&xw[(size_t)s0 * HD + c];
      uint2 v1 = *(const uint2*)&xw[(size_t)s1 * HD + c];
      uint2 v2 = *(const uint2*)&xw[(size_t)s2 * HD + c];
      uint2 v3 = *(const uint2*)&xw[(size_t)s3 * HD + c];
      uint2 v4 = *(const uint2*)&xw[(size_t)s4 * HD + c];
      uint2 v5 = *(const uint2*)&xw[(size_t)s5 * HD + c];
      uint2 v6 = *(const uint2*)&xw[(size_t)s6 * HD + c];
      uint2 v7 = *(const uint2*)&xw[(size_t)s7 * HD + c];
      ACCUMS(v0, d0); ACCUMS(v1, d1); ACCUMS(v2, d2); ACCUMS(v3, d3);
      ACCUMS(v4, d4); ACCUMS(v5, d5); ACCUMS(v6, d6); ACCUMS(v7, d7);
    }
    for (; p < p1; ++p) {
      int s = csr[p];
      float dd = 1.f;
      if constexpr (SRCSCALE) dd = rsqrtf((float)deg[s]);
      uint2 v = *(const uint2*)&xw[(size_t)s * HD + c];
      ACCUMS(v, dd);
    }
#undef ACCUMS
    float dd = rsqrtf((float)dv);
    float4 gv = *(const float4*)&gb[c];
    r0 = fmaxf(dd * a0 + gv.x, 0.f);
    r1 = fmaxf(dd * a1 + gv.y, 0.f);
    r2 = fmaxf(dd * a2 + gv.z, 0.f);
    r3 = fmaxf(dd * a3 + gv.w, 0.f);
    uint2 o;
    o.x = (uint32_t)f2b(r0) | ((uint32_t)f2b(r1) << 16);
    o.y = (uint32_t)f2b(r2) | ((uint32_t)f2b(r3) << 16);
    *(uint2*)&out[(size_t)dst * HD + c] = o;
  }
  // fused BN stats: reduce 4 waves' rows in LDS, one sliced atomic per col
  ss[wave][c + 0] = r0; ss[wave][c + 1] = r1; ss[wave][c + 2] = r2; ss[wave][c + 3] = r3;
  qq[wave][c + 0] = r0 * r0; qq[wave][c + 1] = r1 * r1;
  qq[wave][c + 2] = r2 * r2; qq[wave][c + 3] = r3 * r3;
  __syncthreads();
  int t = threadIdx.x;
  float s = ss[0][t] + ss[1][t] + ss[2][t] + ss[3][t];
  float q = qq[0][t] + qq[1][t] + qq[2][t] + qq[3][t];
  int sl = (blockIdx.x & 7) * 512;
  atomicAdd(&stout[sl + t], s);
  atomicAdd(&stout[sl + 256 + t], q);
}

// ---------------- launch ----------------

extern "C" void kernel_launch(void* const* d_in, const int* in_sizes, int n_in,
                              void* d_out, int out_size, void* d_ws, size_t ws_size,
                              hipStream_t stream) {
  const float* x = (const float*)d_in[0];
  const int* ei = (const int*)d_in[1];
  const float* w1 = (const float*)d_in[2];
  const float* b1 = (const float*)d_in[3];
  const float* g1 = (const float*)d_in[4];
  const float* bt1 = (const float*)d_in[5];
  const float* w2 = (const float*)d_in[6];
  const float* b2 = (const float*)d_in[7];
  const float* g2 = (const float*)d_in[8];
  const float* bt2 = (const float*)d_in[9];
  const float* gw1 = (const float*)d_in[10];
  const float* gb1 = (const float*)d_in[11];
  const float* gg1 = (const float*)d_in[12];
  const float* gbt1 = (const float*)d_in[13];
  const float* gw2 = (const float*)d_in[14];
  const float* gb2 = (const float*)d_in[15];
  const float* gg2 = (const float*)d_in[16];
  const float* gbt2 = (const float*)d_in[17];
  const float* tbW = (const float*)d_in[18];
  const float* tfW = (const float*)d_in[19];
  const float* bb = (const float*)d_in[20];
  const float* bfb = (const float*)d_in[21];
  const int* esrc = ei;
  const int* edst = ei + NEDGES;

  char* wsp = (char*)d_ws;
  size_t off = 0;
  auto alloc = [&](size_t b) {
    void* p = wsp + off;
    off += (b + 511) & ~(size_t)511;
    return p;
  };
  u16* buf1 = (u16*)alloc((size_t)NNODES * HD * 2);
  u16* buf2 = (u16*)alloc((size_t)NNODES * HD * 2);
  u16* csr = (u16*)alloc((size_t)NNODES * CAP * 2);
  int* cur = (int*)alloc((size_t)NNODES * 4);
  float* st = (float*)alloc((size_t)4 * 8 * 512 * 4);   // 4 sets x 8 slices x 512
  u16* W1T = (u16*)alloc(256 * 192 * 2);
  u16* WT = (u16*)alloc(256 * 256 * 2);
  float* Mc = (float*)alloc(256 * 192 * 4);
  float* extra = (float*)alloc(256 * 4);

  float* backc = (float*)d_out;
  float* forec = backc + (size_t)NNODES * 168;
  const float invM = 1.0f / (float)NNODES;

  const int GB = (NNODES + 63) / 64;  // 782
  const int FB3 = 2084;               // fill blocks per third (2084*256 >= 533334)
  const int T1 = 533376;              // FB3*256
  const int T2 = 1066752;             // 2*FB3*256

  setup_k<<<708, 256, 0, stream>>>(cur, csr, st, w1, W1T, tbW, tfW, bb, bfb, Mc);

  // MLP layer 1 (stats fused) + fill of edges [0, T1)
  gemm_k<8, 2, true, true, false, false, true, true><<<GB * 2 + FB3, 256, 0, stream>>>(
      x, NNODES, 192, 168, 168, W1T, b1, nullptr, buf1, nullptr, st,
      esrc, edst, cur, csr, 0, T1);
  // fold BN1 into w2 (+b2)
  fold_k<<<256, 256, 0, stream>>>(st, invM, g1, bt1, w2, 256, b2, WT, extra);
  // MLP layer 2 (stats fused) + fill of edges [T1, T2)
  gemm_k<8, 2, false, true, false, false, true, true><<<GB * 2 + FB3, 256, 0, stream>>>(
      buf1, NNODES, 256, 256, 256, WT, extra, nullptr, buf2, nullptr, st + 4096,
      esrc, edst, cur, csr, T1, T2);
  // fold BN2 into gw1 (no bias: gb1 added after aggregation)
  fold_k<<<256, 256, 0, stream>>>(st + 4096, invM, g2, bt2, gw1, 256, nullptr, WT, extra);
  // xw1 = BN2(a2)@gw1  UNSCALED (DSCALE off: fill still updating cur) +
  // fill of edges [T2, 1.6M) — fill completes by end of this kernel.
  gemm_k<8, 2, false, false, false, false, false, true><<<GB * 2 + FB3, 256, 0, stream>>>(
      buf2, NNODES, 256, 256, 256, WT, extra, nullptr, buf1, nullptr, nullptr,
      esrc, edst, cur, csr, T2, NEDGES);
  // g1a = ReLU(rsqrt(deg[dst]) * sum(rsqrt(deg[src]) * xw1[src]) + gb1)
  agg_k<true><<<12500, 256, 0, stream>>>(csr, cur, buf1, gb1, buf2, st + 8192);
  // fold BN3 into gw2
  fold_k<<<256, 256, 0, stream>>>(st + 8192, invM, gg1, gbt1, gw2, 256, nullptr, WT, extra);
  // xw2 = (BN3(g1a)@gw2) * rsqrt(deg[row])  (fill long complete)
  gemm_k<8, 2, false, false, false, true, false, false><<<GB * 2, 256, 0, stream>>>(
      buf2, NNODES, 256, 256, 256, WT, extra, cur, buf1, nullptr, nullptr,
      nullptr, nullptr, nullptr, nullptr, 0, 0);
  // g2a = ReLU(rsqrt(deg[dst]) * sum(xw2[src]) + gb2), pre-scaled gather
  agg_k<false><<<12500, 256, 0, stream>>>(csr, cur, buf1, gb2, buf2, st + 12288);
  // fold BN4 into Mc [256][192]
  fold_k<<<192, 256, 0, stream>>>(st + 12288, invM, gg2, gbt2, Mc, 192, nullptr, WT, extra);
  // final: [backcast || forecast] = BN4(g2a) @ Mc (2 col-blocks of 96)
  gemm_k<6, 2, false, false, true, false, false, false><<<GB * 2, 256, 0, stream>>>(
      buf2, NNODES, 256, 256, 256, WT, extra, nullptr, backc, forec, nullptr,
      nullptr, nullptr, nullptr, nullptr, 0, 0);
}